// Round 20
// baseline (510.864 us; speedup 1.0000x reference)
//
#include <hip/hip_runtime.h>
#include <hip/hip_bf16.h>
#include <math.h>

#define N_ROWS 65536
#define P_DIM  256
#define C_DIM  3
#define U_DIM  512
#define NPLANES 7

#define BM 32
#define BU 64
#define NUT (U_DIM / BU)               // 8 u-tiles, persistent per block

typedef __attribute__((ext_vector_type(8))) short short8;     // 8 bf16 = 4 VGPR
typedef __attribute__((ext_vector_type(4))) float f32x4;
typedef __attribute__((ext_vector_type(4))) float floatx4;
typedef __attribute__((ext_vector_type(4))) unsigned int uint4v;

static __device__ __forceinline__ unsigned short f2bf(float f) {
    unsigned int u = __builtin_bit_cast(unsigned int, f);
    u += 0x7FFFu + ((u >> 16) & 1u);      // RNE
    return (unsigned short)(u >> 16);
}

// E[relu(N(m, v))]; exact relu when v == 0.
// ONE transcendental: t = sigma(1.702 w) approximates Phi(w); its derivative
// 1.702*t^2*e (e = exp(-1.702 w)) approximates pdf(w). val = s*pdf + m*Phi.
static __device__ __forceinline__ float erl(float m, float v) {
    float r = __builtin_amdgcn_rsqf(fmaxf(v, 1e-20f));
    float w = m * r;
    float s = v * r;                                   // sqrt(v)
    float e = __expf(w * -1.702f);
    float t = __builtin_amdgcn_rcpf(1.0f + e);
    float val = fmaf(m, t, 1.702f * s * t * t * e);
    return (v > 0.0f) ? val : fmaxf(m, 0.0f);
}

// ---------------- prep: fragment-packed B (7 planes) + q-tables (R15-proven) ------
// Bf[ut][wc][ks][pl][lane][e]: the exact 1KB a wave reads per (ut,wc,ks,pl) is
// CONTIGUOUS (addr = base + lane*16B) -> 8 cache lines per load inst, not 64.
//   u = ut*64 + wc*16 + (lane&15);  k = ks*32 + (lane>>4)*8 + e
// plane 0: kernel[k][u]; 1+c: mu[k][c]*kernel; 4+c: var[k][c]*kernel^2
// qtab[p] = 3 float4: a_c = 1/(2v), b_c = -2 m a, d_c = m^2 a + 0.5 log(2 pi v)
__global__ __launch_bounds__(512) void prep_kernel(
    const float* __restrict__ cmeans, const float* __restrict__ cvars,
    const float* __restrict__ kern, unsigned short* __restrict__ Bf,
    float* __restrict__ qtab)
{
    int tid = blockIdx.x * 512 + threadIdx.x;
    const int TOTAL_B = NPLANES * U_DIM * P_DIM;   // 917504
    if (tid < TOTAL_B) {
        int e    = tid & 7;
        int lane = (tid >> 3) & 63;
        int rest = tid >> 9;          // 0..1791
        int pl   = rest % 7;
        int rk   = rest / 7;          // 0..255
        int ks   = rk & 7;
        int uw   = rk >> 3;           // 0..31
        int wc   = uw & 3;
        int ut   = uw >> 2;
        int u = ut * 64 + wc * 16 + (lane & 15);
        int k = ks * 32 + (lane >> 4) * 8 + e;
        float kv = kern[k * U_DIM + u];
        float val;
        if (pl == 0)      val = kv;
        else if (pl <= 3) val = cmeans[k * C_DIM + (pl - 1)] * kv;
        else              val = cvars[k * C_DIM + (pl - 4)] * (kv * kv);
        Bf[tid] = f2bf(val);
    } else if (tid - TOTAL_B < P_DIM) {
        int p = tid - TOTAL_B;
        float a[3], b[3], d[3];
#pragma unroll
        for (int c = 0; c < 3; ++c) {
            float m = cmeans[p * 3 + c];
            float v = cvars[p * 3 + c];
            float iv = 0.5f / v;
            a[c] = iv;
            b[c] = -2.0f * m * iv;
            d[c] = m * m * iv + 0.5f * logf(2.0f * 3.14159265359f * v);
        }
        float* q = qtab + p * 12;
        q[0] = a[0]; q[1] = a[1]; q[2]  = a[2]; q[3]  = 0.f;
        q[4] = b[0]; q[5] = b[1]; q[6]  = b[2]; q[7]  = 0.f;
        q[8] = d[0]; q[9] = d[1]; q[10] = d[2]; q[11] = 0.f;
    }
}

// load 7 B-plane fragments from rolling base (all offsets fold into 13-bit imm)
#define LOADBP(base, dst) do {                                                \
    const unsigned short* _b0 = (base);                                       \
    const unsigned short* _b1 = (base) + 2048;                                \
    dst[0] = *(const short8*)(_b0);                                           \
    dst[1] = *(const short8*)(_b0 + 512);                                     \
    dst[2] = *(const short8*)(_b0 + 1024);                                    \
    dst[3] = *(const short8*)(_b0 + 1536);                                    \
    dst[4] = *(const short8*)(_b1);                                           \
    dst[5] = *(const short8*)(_b1 + 512);                                     \
    dst[6] = *(const short8*)(_b1 + 1024);                                    \
} while (0)

// one k-step: 4 contiguous (conflict-free) LDS A-reads + 14 MFMAs
// fragment-ordered LDS layout: elem = rowblk*4096 + ks*512 + lk*128 + r16*8
#define STEP(breg, ksi) do {                                                  \
    __builtin_amdgcn_s_setprio(1);                                            \
    _Pragma("unroll")                                                         \
    for (int r = 0; r < 2; ++r) {                                             \
        short8 a0 = *(const short8*)&xs[aBase + r * 4096 + (ksi) * 512];      \
        short8 a1 = *(const short8*)&mk[aBase + r * 4096 + (ksi) * 512];      \
        acc[0][r] = __builtin_amdgcn_mfma_f32_16x16x32_bf16(a0, breg[0], acc[0][r], 0, 0, 0); \
        _Pragma("unroll")                                                     \
        for (int pl = 1; pl < NPLANES; ++pl)                                  \
            acc[pl][r] = __builtin_amdgcn_mfma_f32_16x16x32_bf16(a1, breg[pl], acc[pl][r], 0, 0, 0); \
    }                                                                         \
    __builtin_amdgcn_s_setprio(0);                                            \
} while (0)

// ---------------- main: BM=32, 256 threads = 4 waves (4 wc), 4 blocks/CU ----------
// R19 champion + FUSED stage/loglik: X is read once; q-partials accumulate during
// the bf16 conversion, land in deterministic qacc[row][slot], finalized by 32 threads.
__global__ __launch_bounds__(256, 4) void main_kernel(
    const float* __restrict__ X, const unsigned short* __restrict__ Bf,
    const float* __restrict__ qtab, const float* __restrict__ logits,
    const float* __restrict__ bias, float* __restrict__ out)
{
    __shared__ unsigned short xs[BM * P_DIM];   // x_safe bf16, frag-ordered (16 KB)
    __shared__ unsigned short mk[BM * P_DIM];   // mask   bf16, frag-ordered (16 KB)
    __shared__ float qacc[BM][8][3];            // loglik partials           (3 KB)
    __shared__ float pws[BM][3];                // softmax weights           (0.38 KB)

    const int tid = threadIdx.x;
    const int n0 = blockIdx.x * BM;
    const int lane = tid & 63;
    const int wid  = tid >> 6;     // 0..3
    const int l15  = lane & 15;
    const int lk   = lane >> 4;    // 0..3

    // ---- fused stage + loglik partials: thread covers 32 elems of one row ----
    {
        const int rowblk = wid >> 1;         // 0..1
        const int ksh    = (wid & 1) * 4;
        const int row    = rowblk * 16 + l15;
        const int slot   = (wid & 1) * 4 + lk;   // 0..7, unique per (row,thread)
        const float* Xb = X + (size_t)(n0 + row) * P_DIM + lk * 8;
        const int ebase = rowblk * 4096 + lk * 128 + l15 * 8;   // + ks*512
        float a0 = 0.f, a1 = 0.f, a2 = 0.f;
#pragma unroll
        for (int j = 0; j < 4; ++j) {
            int ks = ksh + j;
            floatx4 v0 = *(const floatx4*)(Xb + ks * 32);
            floatx4 v1 = *(const floatx4*)(Xb + ks * 32 + 4);
            const float* qt = qtab + (size_t)(ks * 32 + lk * 8) * 12;
            unsigned int wx[4], wm[4];
#pragma unroll
            for (int h = 0; h < 2; ++h) {
                floatx4 v = h ? v1 : v0;
#pragma unroll
                for (int e = 0; e < 2; ++e) {
                    float f0 = v[2 * e], f1 = v[2 * e + 1];
                    int e0i = h * 4 + 2 * e, e1i = e0i + 1;
                    bool na0 = !(f0 == f0), na1 = !(f1 == f1);
                    unsigned int s0 = na0 ? 0u : (unsigned int)f2bf(f0);
                    unsigned int s1 = na1 ? 0u : (unsigned int)f2bf(f1);
                    unsigned int m0 = na0 ? 0x3F80u : 0u;
                    unsigned int m1 = na1 ? 0x3F80u : 0u;
                    wx[h * 2 + e] = s0 | (s1 << 16);
                    wm[h * 2 + e] = m0 | (m1 << 16);
                    // loglik partials: q = (a*xv + b)*xv + vd*d
                    float xv0 = na0 ? 0.f : f0, vd0 = na0 ? 0.f : 1.f;
                    float xv1 = na1 ? 0.f : f1, vd1 = na1 ? 0.f : 1.f;
                    floatx4 qa = *(const floatx4*)(qt + e0i * 12);
                    floatx4 qb = *(const floatx4*)(qt + e0i * 12 + 4);
                    floatx4 qd = *(const floatx4*)(qt + e0i * 12 + 8);
                    a0 = fmaf(vd0, qd[0], fmaf(fmaf(qa[0], xv0, qb[0]), xv0, a0));
                    a1 = fmaf(vd0, qd[1], fmaf(fmaf(qa[1], xv0, qb[1]), xv0, a1));
                    a2 = fmaf(vd0, qd[2], fmaf(fmaf(qa[2], xv0, qb[2]), xv0, a2));
                    qa = *(const floatx4*)(qt + e1i * 12);
                    qb = *(const floatx4*)(qt + e1i * 12 + 4);
                    qd = *(const floatx4*)(qt + e1i * 12 + 8);
                    a0 = fmaf(vd1, qd[0], fmaf(fmaf(qa[0], xv1, qb[0]), xv1, a0));
                    a1 = fmaf(vd1, qd[1], fmaf(fmaf(qa[1], xv1, qb[1]), xv1, a1));
                    a2 = fmaf(vd1, qd[2], fmaf(fmaf(qa[2], xv1, qb[2]), xv1, a2));
                }
            }
            uint4v px = {wx[0], wx[1], wx[2], wx[3]};
            uint4v pm = {wm[0], wm[1], wm[2], wm[3]};
            *(uint4v*)&xs[ebase + ks * 512] = px;
            *(uint4v*)&mk[ebase + ks * 512] = pm;
        }
        qacc[row][slot][0] = a0;
        qacc[row][slot][1] = a1;
        qacc[row][slot][2] = a2;
    }
    __syncthreads();

    // ---- finalize softmax: one thread per row (deterministic 8-slot sum) ----
    if (tid < BM) {
        float s0 = 0.f, s1 = 0.f, s2 = 0.f;
#pragma unroll
        for (int sl = 0; sl < 8; ++sl) {
            s0 += qacc[tid][sl][0];
            s1 += qacc[tid][sl][1];
            s2 += qacc[tid][sl][2];
        }
        float z0 = logits[0] - s0;
        float z1 = logits[1] - s1;
        float z2 = logits[2] - s2;
        float mx = fmaxf(z0, fmaxf(z1, z2));
        float e0 = __expf(z0 - mx), e1 = __expf(z1 - mx), e2 = __expf(z2 - mx);
        float inv = __builtin_amdgcn_rcpf(e0 + e1 + e2);
        pws[tid][0] = e0 * inv;
        pws[tid][1] = e1 * inv;
        pws[tid][2] = e2 * inv;
    }
    __syncthreads();

    // ---- persistent u-loop: rolling single-buffer packed-B k-loop + erl epilogue ----
    const int wc = wid;            // 0..3 : 16-col group (all waves share the 32 rows)
    const int aBase = lk * 128 + l15 * 8;     // + r*4096 + ks*512
    // block-decorrelated stagger: co-resident blocks start at different u-tiles
    const int phase = (int)(((unsigned)(wc + blockIdx.x) & 3u) << 1);

    short8 bR[NPLANES];
    const unsigned short* nextp;
    // prologue: first ut's ks=0 loads; nextp -> ks=1 data
    {
        const int utf = phase & (NUT - 1);
        const unsigned short* bpw0 = Bf + ((size_t)(utf * 4 + wc) * (8 * 7 * 512)) + (size_t)lane * 8;
        LOADBP(bpw0, bR);
        nextp = bpw0 + 3584;
    }

#pragma unroll 1
    for (int ut0 = 0; ut0 < NUT; ++ut0) {
        const int ut  = (ut0 + phase) & (NUT - 1);
        const int utn = (ut0 + 1 + phase) & (NUT - 1);
        const unsigned short* bpwn = Bf + ((size_t)(utn * 4 + wc) * (8 * 7 * 512)) + (size_t)lane * 8;

        f32x4 acc[NPLANES][2];
#pragma unroll
        for (int pl = 0; pl < NPLANES; ++pl)
#pragma unroll
            for (int r = 0; r < 2; ++r)
                acc[pl][r] = (f32x4){0.f, 0.f, 0.f, 0.f};

#pragma unroll 1
        for (int ks = 0; ks < 8; ++ks) {
            STEP(bR, ks);                         // consume bR (loaded last iter)
            LOADBP(nextp, bR);                    // prefetch ks+1 / next ut's ks=0
            nextp = (ks == 6) ? bpwn : (nextp + 3584);
            __builtin_amdgcn_sched_barrier(0);    // pin loads here (don't sink to use)
        }

        // epilogue (next ut's ks=0 loads in flight underneath):
        // D lane map col = lane&15, row = 4*(lane>>4)+q (+ r*16)
        const int ucol = ut * BU + wc * 16 + l15;
        const float bias_u = bias[ucol];
#pragma unroll
        for (int r = 0; r < 2; ++r) {
            int rloc = r * 16 + 4 * lk;
#pragma unroll
            for (int q = 0; q < 4; ++q) {
                int rl = rloc + q;
                float p0 = pws[rl][0], p1 = pws[rl][1], p2 = pws[rl][2];
                float y0 = acc[0][r][q] + bias_u;
                float res = p0 * erl(y0 + acc[1][r][q], acc[4][r][q])
                          + p1 * erl(y0 + acc[2][r][q], acc[5][r][q])
                          + p2 * erl(y0 + acc[3][r][q], acc[6][r][q]);
                out[(size_t)(n0 + rl) * U_DIM + ucol] = res;
            }
        }
    }
}

extern "C" void kernel_launch(void* const* d_in, const int* in_sizes, int n_in,
                              void* d_out, int out_size, void* d_ws, size_t ws_size,
                              hipStream_t stream)
{
    const float* X      = (const float*)d_in[0];
    const float* cmeans = (const float*)d_in[1];
    const float* cvars  = (const float*)d_in[2];
    const float* logits = (const float*)d_in[3];
    const float* kern   = (const float*)d_in[4];
    const float* bias   = (const float*)d_in[5];
    float* out = (float*)d_out;

    char* wsb = (char*)d_ws;
    unsigned short* Bf = (unsigned short*)wsb;                 // 1,835,008 B
    float* qtab = (float*)(wsb + 1835008);                     //    12,288 B

    hipLaunchKernelGGL(prep_kernel, dim3(1794), dim3(512), 0, stream,
                       cmeans, cvars, kern, Bf, qtab);
    hipLaunchKernelGGL(main_kernel, dim3(N_ROWS / BM), dim3(256), 0, stream,
                       X, Bf, qtab, logits, bias, out);
}

// Round 21
// 236.535 us; speedup vs baseline: 2.1598x; 2.1598x over previous
//
#include <hip/hip_runtime.h>
#include <hip/hip_bf16.h>
#include <math.h>

#define N_ROWS 65536
#define P_DIM  256
#define C_DIM  3
#define U_DIM  512
#define NPLANES 7

#define BM 32
#define BU 64
#define NUT (U_DIM / BU)               // 8 u-tiles, persistent per block

typedef __attribute__((ext_vector_type(8))) short short8;     // 8 bf16 = 4 VGPR
typedef __attribute__((ext_vector_type(4))) float f32x4;
typedef __attribute__((ext_vector_type(4))) float floatx4;
typedef __attribute__((ext_vector_type(4))) unsigned int uint4v;

static __device__ __forceinline__ unsigned short f2bf(float f) {
    unsigned int u = __builtin_bit_cast(unsigned int, f);
    u += 0x7FFFu + ((u >> 16) & 1u);      // RNE
    return (unsigned short)(u >> 16);
}

// E[relu(N(m, v))]; exact relu when v == 0.
// ONE transcendental: t = sigma(1.702 w) approximates Phi(w); its derivative
// 1.702*t^2*e (e = exp(-1.702 w)) approximates pdf(w). val = s*pdf + m*Phi.
// max |err| ~ s*0.027 ~ 0.011 -- well under the 0.105 threshold margin.
static __device__ __forceinline__ float erl(float m, float v) {
    float r = __builtin_amdgcn_rsqf(fmaxf(v, 1e-20f));
    float w = m * r;
    float s = v * r;                                   // sqrt(v)
    float e = __expf(w * -1.702f);
    float t = __builtin_amdgcn_rcpf(1.0f + e);
    float val = fmaf(m, t, 1.702f * s * t * t * e);
    return (v > 0.0f) ? val : fmaxf(m, 0.0f);
}

// ---------------- prep: fragment-packed B (7 planes) + q-tables (R15-proven) ------
// Bf[ut][wc][ks][pl][lane][e]: the exact 1KB a wave reads per (ut,wc,ks,pl) is
// CONTIGUOUS (addr = base + lane*16B) -> 8 cache lines per load inst, not 64.
//   u = ut*64 + wc*16 + (lane&15);  k = ks*32 + (lane>>4)*8 + e
// plane 0: kernel[k][u]; 1+c: mu[k][c]*kernel; 4+c: var[k][c]*kernel^2
// qtab[p] = 3 float4: a_c = 1/(2v), b_c = -2 m a, d_c = m^2 a + 0.5 log(2 pi v)
__global__ __launch_bounds__(512) void prep_kernel(
    const float* __restrict__ cmeans, const float* __restrict__ cvars,
    const float* __restrict__ kern, unsigned short* __restrict__ Bf,
    float* __restrict__ qtab)
{
    int tid = blockIdx.x * 512 + threadIdx.x;
    const int TOTAL_B = NPLANES * U_DIM * P_DIM;   // 917504
    if (tid < TOTAL_B) {
        int e    = tid & 7;
        int lane = (tid >> 3) & 63;
        int rest = tid >> 9;          // 0..1791
        int pl   = rest % 7;
        int rk   = rest / 7;          // 0..255
        int ks   = rk & 7;
        int uw   = rk >> 3;           // 0..31
        int wc   = uw & 3;
        int ut   = uw >> 2;
        int u = ut * 64 + wc * 16 + (lane & 15);
        int k = ks * 32 + (lane >> 4) * 8 + e;
        float kv = kern[k * U_DIM + u];
        float val;
        if (pl == 0)      val = kv;
        else if (pl <= 3) val = cmeans[k * C_DIM + (pl - 1)] * kv;
        else              val = cvars[k * C_DIM + (pl - 4)] * (kv * kv);
        Bf[tid] = f2bf(val);
    } else if (tid - TOTAL_B < P_DIM) {
        int p = tid - TOTAL_B;
        float a[3], b[3], d[3];
#pragma unroll
        for (int c = 0; c < 3; ++c) {
            float m = cmeans[p * 3 + c];
            float v = cvars[p * 3 + c];
            float iv = 0.5f / v;
            a[c] = iv;
            b[c] = -2.0f * m * iv;
            d[c] = m * m * iv + 0.5f * logf(2.0f * 3.14159265359f * v);
        }
        float* q = qtab + p * 12;
        q[0] = a[0]; q[1] = a[1]; q[2]  = a[2]; q[3]  = 0.f;
        q[4] = b[0]; q[5] = b[1]; q[6]  = b[2]; q[7]  = 0.f;
        q[8] = d[0]; q[9] = d[1]; q[10] = d[2]; q[11] = 0.f;
    }
}

// load 7 B-plane fragments from rolling base (all offsets fold into 13-bit imm:
// base covers pl 0..3 at 0/1024/2048/3072 B; base+4KB covers pl 4..6 at 0/1024/2048 B)
#define LOADBP(base, dst) do {                                                \
    const unsigned short* _b0 = (base);                                       \
    const unsigned short* _b1 = (base) + 2048;                                \
    dst[0] = *(const short8*)(_b0);                                           \
    dst[1] = *(const short8*)(_b0 + 512);                                     \
    dst[2] = *(const short8*)(_b0 + 1024);                                    \
    dst[3] = *(const short8*)(_b0 + 1536);                                    \
    dst[4] = *(const short8*)(_b1);                                           \
    dst[5] = *(const short8*)(_b1 + 512);                                     \
    dst[6] = *(const short8*)(_b1 + 1024);                                    \
} while (0)

// one k-step: 4 contiguous (conflict-free) LDS A-reads + 14 MFMAs
// fragment-ordered LDS layout: elem = rowblk*4096 + ks*512 + lk*128 + r16*8
#define STEP(breg, ksi) do {                                                  \
    __builtin_amdgcn_s_setprio(1);                                            \
    _Pragma("unroll")                                                         \
    for (int r = 0; r < 2; ++r) {                                             \
        short8 a0 = *(const short8*)&xs[aBase + r * 4096 + (ksi) * 512];      \
        short8 a1 = *(const short8*)&mk[aBase + r * 4096 + (ksi) * 512];      \
        acc[0][r] = __builtin_amdgcn_mfma_f32_16x16x32_bf16(a0, breg[0], acc[0][r], 0, 0, 0); \
        _Pragma("unroll")                                                     \
        for (int pl = 1; pl < NPLANES; ++pl)                                  \
            acc[pl][r] = __builtin_amdgcn_mfma_f32_16x16x32_bf16(a1, breg[pl], acc[pl][r], 0, 0, 0); \
    }                                                                         \
    __builtin_amdgcn_s_setprio(0);                                            \
} while (0)

// ---------------- main: BM=32, 256 threads = 4 waves (4 wc), 4 blocks/CU ----------
// R17/R18 champion structure + rolling B prefetch with imm-folded addressing +
// block-decorrelated ut phase. Per wave: acc[7][2]=56 AGPR + 28-reg B buffer
// (proven no-spill shape).
__global__ __launch_bounds__(256, 4) void main_kernel(
    const float* __restrict__ X, const unsigned short* __restrict__ Bf,
    const float* __restrict__ qtab, const float* __restrict__ logits,
    const float* __restrict__ bias, float* __restrict__ out)
{
    __shared__ unsigned short xs[BM * P_DIM];   // x_safe bf16, frag-ordered (16 KB)
    __shared__ unsigned short mk[BM * P_DIM];   // mask   bf16, frag-ordered (16 KB)
    __shared__ float pws[BM][3];                // softmax weights           (0.38 KB)

    const int tid = threadIdx.x;
    const int n0 = blockIdx.x * BM;
    const int lane = tid & 63;
    const int wid  = tid >> 6;     // 0..3
    const int l15  = lane & 15;
    const int lk   = lane >> 4;    // 0..3

    // ---- stage x tile: wave pair (wid>>1) owns rowblk (16 rows); wid&1 owns ks-half ----
    {
        const int rowblk = wid >> 1;         // 0..1
        const int ksh    = (wid & 1) * 4;
        const float* Xb = X + (size_t)(n0 + rowblk * 16 + l15) * P_DIM + lk * 8;
        const int ebase = rowblk * 4096 + lk * 128 + l15 * 8;   // + ks*512
#pragma unroll
        for (int j = 0; j < 4; ++j) {
            int ks = ksh + j;
            floatx4 v0 = *(const floatx4*)(Xb + ks * 32);
            floatx4 v1 = *(const floatx4*)(Xb + ks * 32 + 4);
            unsigned int wx[4], wm[4];
#pragma unroll
            for (int h = 0; h < 2; ++h) {
                floatx4 v = h ? v1 : v0;
#pragma unroll
                for (int e = 0; e < 2; ++e) {
                    float f0 = v[2 * e], f1 = v[2 * e + 1];
                    bool na0 = !(f0 == f0), na1 = !(f1 == f1);
                    unsigned int s0 = na0 ? 0u : (unsigned int)f2bf(f0);
                    unsigned int s1 = na1 ? 0u : (unsigned int)f2bf(f1);
                    unsigned int m0 = na0 ? 0x3F80u : 0u;
                    unsigned int m1 = na1 ? 0x3F80u : 0u;
                    wx[h * 2 + e] = s0 | (s1 << 16);
                    wm[h * 2 + e] = m0 | (m1 << 16);
                }
            }
            uint4v px = {wx[0], wx[1], wx[2], wx[3]};
            uint4v pm = {wm[0], wm[1], wm[2], wm[3]};
            *(uint4v*)&xs[ebase + ks * 512] = px;
            *(uint4v*)&mk[ebase + ks * 512] = pm;
        }
    }

    // ---- fused loglik + softmax via q-tables: 8 threads per row -> pws[row][3] ----
    {
        int row = tid >> 3;          // 0..31
        int sub = tid & 7;
        const floatx4* xr = (const floatx4*)(X + (size_t)(n0 + row) * P_DIM);
        const floatx4* qt = (const floatx4*)qtab;
        float a0 = 0.f, a1 = 0.f, a2 = 0.f;
#pragma unroll
        for (int i = 0; i < 8; ++i) {
            floatx4 v = xr[sub * 8 + i];
#pragma unroll
            for (int e = 0; e < 4; ++e) {
                float x = v[e];
                int p = sub * 32 + i * 4 + e;
                bool valid = (x == x);
                float xv = valid ? x : 0.f;
                floatx4 qa = qt[p * 3 + 0];
                floatx4 qb = qt[p * 3 + 1];
                floatx4 qd = qt[p * 3 + 2];
                float q0 = fmaf(fmaf(qa[0], xv, qb[0]), xv, qd[0]);
                float q1 = fmaf(fmaf(qa[1], xv, qb[1]), xv, qd[1]);
                float q2 = fmaf(fmaf(qa[2], xv, qb[2]), xv, qd[2]);
                a0 += valid ? q0 : 0.f;
                a1 += valid ? q1 : 0.f;
                a2 += valid ? q2 : 0.f;
            }
        }
#pragma unroll
        for (int off = 1; off < 8; off <<= 1) {
            a0 += __shfl_xor(a0, off);
            a1 += __shfl_xor(a1, off);
            a2 += __shfl_xor(a2, off);
        }
        if (sub == 0) {
            float z0 = logits[0] - a0;
            float z1 = logits[1] - a1;
            float z2 = logits[2] - a2;
            float mx = fmaxf(z0, fmaxf(z1, z2));
            float e0 = __expf(z0 - mx), e1 = __expf(z1 - mx), e2 = __expf(z2 - mx);
            float inv = __builtin_amdgcn_rcpf(e0 + e1 + e2);
            pws[row][0] = e0 * inv;
            pws[row][1] = e1 * inv;
            pws[row][2] = e2 * inv;
        }
    }
    __syncthreads();

    // ---- persistent u-loop: rolling single-buffer packed-B k-loop + erl epilogue ----
    const int wc = wid;            // 0..3 : 16-col group (all waves share the 32 rows)
    const int aBase = lk * 128 + l15 * 8;     // + r*4096 + ks*512
    // block-decorrelated stagger: co-resident blocks start at different u-tiles
    const int phase = (int)(((unsigned)(wc + blockIdx.x) & 3u) << 1);

    short8 bR[NPLANES];
    const unsigned short* nextp;
    // prologue: first ut's ks=0 loads; nextp -> ks=1 data
    {
        const int utf = phase & (NUT - 1);
        const unsigned short* bpw0 = Bf + ((size_t)(utf * 4 + wc) * (8 * 7 * 512)) + (size_t)lane * 8;
        LOADBP(bpw0, bR);
        nextp = bpw0 + 3584;
    }

#pragma unroll 1
    for (int ut0 = 0; ut0 < NUT; ++ut0) {
        const int ut  = (ut0 + phase) & (NUT - 1);
        const int utn = (ut0 + 1 + phase) & (NUT - 1);
        const unsigned short* bpwn = Bf + ((size_t)(utn * 4 + wc) * (8 * 7 * 512)) + (size_t)lane * 8;

        f32x4 acc[NPLANES][2];
#pragma unroll
        for (int pl = 0; pl < NPLANES; ++pl)
#pragma unroll
            for (int r = 0; r < 2; ++r)
                acc[pl][r] = (f32x4){0.f, 0.f, 0.f, 0.f};

#pragma unroll 1
        for (int ks = 0; ks < 8; ++ks) {
            STEP(bR, ks);                         // consume bR (loaded last iter)
            LOADBP(nextp, bR);                    // prefetch ks+1 / next ut's ks=0
            nextp = (ks == 6) ? bpwn : (nextp + 3584);
            __builtin_amdgcn_sched_barrier(0);    // pin loads here (don't sink to use)
        }
        // after ks=7: nextp = bpwn + 3584 (next ut's ks=1), bR holds next ut's ks=0

        // epilogue (next ut's ks=0 loads in flight underneath):
        // D lane map col = lane&15, row = 4*(lane>>4)+q (+ r*16)
        const int ucol = ut * BU + wc * 16 + l15;
        const float bias_u = bias[ucol];
#pragma unroll
        for (int r = 0; r < 2; ++r) {
            int rloc = r * 16 + 4 * lk;
#pragma unroll
            for (int q = 0; q < 4; ++q) {
                int rl = rloc + q;
                float p0 = pws[rl][0], p1 = pws[rl][1], p2 = pws[rl][2];
                float y0 = acc[0][r][q] + bias_u;
                float res = p0 * erl(y0 + acc[1][r][q], acc[4][r][q])
                          + p1 * erl(y0 + acc[2][r][q], acc[5][r][q])
                          + p2 * erl(y0 + acc[3][r][q], acc[6][r][q]);
                out[(size_t)(n0 + rl) * U_DIM + ucol] = res;
            }
        }
    }
}

extern "C" void kernel_launch(void* const* d_in, const int* in_sizes, int n_in,
                              void* d_out, int out_size, void* d_ws, size_t ws_size,
                              hipStream_t stream)
{
    const float* X      = (const float*)d_in[0];
    const float* cmeans = (const float*)d_in[1];
    const float* cvars  = (const float*)d_in[2];
    const float* logits = (const float*)d_in[3];
    const float* kern   = (const float*)d_in[4];
    const float* bias   = (const float*)d_in[5];
    float* out = (float*)d_out;

    char* wsb = (char*)d_ws;
    unsigned short* Bf = (unsigned short*)wsb;                 // 1,835,008 B
    float* qtab = (float*)(wsb + 1835008);                     //    12,288 B

    hipLaunchKernelGGL(prep_kernel, dim3(1794), dim3(512), 0, stream,
                       cmeans, cvars, kern, Bf, qtab);
    hipLaunchKernelGGL(main_kernel, dim3(N_ROWS / BM), dim3(256), 0, stream,
                       X, Bf, qtab, logits, bias, out);
}